// Round 7
// baseline (281.635 us; speedup 1.0000x reference)
//
#include <hip/hip_runtime.h>
#include <hip/hip_fp16.h>
#include <stdint.h>

#define EPS_BN 1e-5f

constexpr int Fn = 32;    // frames
constexpr int Pn = 64;    // peds per frame
constexpr int Bn = 2048;  // batch
constexpr int Hn = 128;   // h_dim
constexpr int En = 64;    // embed dim
constexpr int Mn = 512;   // GEMM K
constexpr int Dn = 1024;  // GEMM N

using f16x8   = __attribute__((ext_vector_type(8))) _Float16;
using f32x16  = __attribute__((ext_vector_type(16))) float;

static __device__ __forceinline__ unsigned short hfbits(float f) {
  return __builtin_bit_cast(unsigned short, __float2half(f));
}

// async 16B/lane global -> LDS (LDS base wave-uniform; HW adds lane*16)
static __device__ __forceinline__ void dma16(const uint4* g, const uint4* l) {
  __builtin_amdgcn_global_load_lds(
      (const __attribute__((address_space(1))) unsigned int*)g,
      (__attribute__((address_space(3))) unsigned int*)l, 16, 0, 0);
}

// packed fp16 max: one VOP3P instruction (ROCm header lacks __hmax2)
static __device__ __forceinline__ uint32_t pkmax(uint32_t a, uint32_t b) {
  uint32_t r;
  asm("v_pk_max_f16 %0, %1, %2" : "=v"(r) : "v"(a), "v"(b));
  return r;
}

// r0/r1 = fp16 max(a0,q), max(a1,q): 8 instructions total.
static __device__ __forceinline__ void mk2(uint4 a0, uint4 a1, uint4 q,
                                           f16x8& r0, f16x8& r1) {
  uint4 x0, x1;
#pragma unroll
  for (int v = 0; v < 4; ++v) {
    uint32_t qw = ((const uint32_t*)&q)[v];
    ((uint32_t*)&x0)[v] = pkmax(((const uint32_t*)&a0)[v], qw);
    ((uint32_t*)&x1)[v] = pkmax(((const uint32_t*)&a1)[v], qw);
  }
  r0 = __builtin_bit_cast(f16x8, x0);
  r1 = __builtin_bit_cast(f16x8, x1);
}

// ---------------------------------------------------------------------------
// prep_all: 656 blocks x 512 threads (merged back — R6 split located nothing
// big in prep; splitting cost ~6us of extra launch gaps).
// ---------------------------------------------------------------------------
__global__ void prep_all(const float* __restrict__ hs, const float* __restrict__ pos,
                         const float* __restrict__ We, const float* __restrict__ be,
                         const float* __restrict__ W1, const float* __restrict__ b1,
                         const float* __restrict__ g1, const float* __restrict__ beta1,
                         const float* __restrict__ rm1, const float* __restrict__ rv1,
                         const float* __restrict__ W2, const float* __restrict__ b2,
                         const float* __restrict__ g2, const float* __restrict__ beta2,
                         const float* __restrict__ rm2, const float* __restrict__ rv2,
                         __half* __restrict__ Agb, __half* __restrict__ Qgb,
                         uint4* __restrict__ W2g, float* __restrict__ G0,
                         float* __restrict__ G1, float* __restrict__ c2) {
  __shared__ float smem[64 * 65];
  int bid = blockIdx.x, t = threadIdx.x;
  if (bid < 512) {
    // ---- Ag/Qg for 4 batch rows, no LDS ----
    int rb = bid * 4, m = t;
    float w0 = 0.f, w1 = 0.f, c = 0.f;
    for (int e = 0; e < En; ++e) {
      float w = W1[e * Mn + m];
      w0 += We[e] * w; w1 += We[En + e] * w; c += be[e] * w;
    }
    c += b1[m];
    float s  = g1[m] * rsqrtf(rv1[m] + EPS_BN);
    float tt = beta1[m] - rm1[m] * s;
    float acc[4];
#pragma unroll
    for (int ri = 0; ri < 4; ++ri) acc[ri] = c;
#pragma unroll 4
    for (int e = 0; e < Hn; ++e) {
      float w = W1[(En + e) * Mn + m];
#pragma unroll
      for (int ri = 0; ri < 4; ++ri)
        acc[ri] += hs[(rb + ri) * Hn + e] * w;   // uniform addr -> s_load
    }
#pragma unroll
    for (int ri = 0; ri < 4; ++ri) {
      float q = pos[(rb + ri) * 2] * w0 + pos[(rb + ri) * 2 + 1] * w1;  // uniform
      Agb[(rb + ri) * Mn + m] = __float2half((acc[ri] + q) * s + tt);
      Qgb[(rb + ri) * Mn + m] = __float2half(q * s);
    }
  } else if (bid < 640) {
    // ---- W2 -> 32-col B-fragment granules (s2 folded), fp16 ----
    int b2i = bid - 512;                 // 0..127
    int d0 = (b2i & 15) * 64, k0 = (b2i >> 4) * 64;
    int col = t & 63, row8 = t >> 6;
#pragma unroll
    for (int rr = 0; rr < 8; ++rr) {
      int row = rr * 8 + row8;
      smem[row * 65 + col] = W2[(k0 + row) * Dn + d0 + col];  // [k_local][d_local]
    }
    __syncthreads();
    int lane = t & 63, q8 = t >> 6;
    int sel_n = q8 & 1, sel_ks = q8 >> 1;
    int dl = sel_n * 32 + (lane & 31), d = d0 + dl;
    float sf = g2[d] * rsqrtf(rv2[d] + EPS_BN);
    int kb = sel_ks * 16 + (lane >> 5) * 8;
    uint32_t wd[4];
#pragma unroll
    for (int h = 0; h < 4; ++h) {
      uint32_t u0 = hfbits(smem[(kb + 2 * h) * 65 + dl] * sf);
      uint32_t u1 = hfbits(smem[(kb + 2 * h + 1) * 65 + dl] * sf);
      wd[h] = u0 | (u1 << 16);
    }
    int n32 = (d0 >> 5) + sel_n;
    int ks  = (k0 >> 4) + sel_ks;
    W2g[(n32 * 32 + ks) * 64 + lane] = (uint4){wd[0], wd[1], wd[2], wd[3]};
  } else {
    // ---- G slice (64 d-cols) + c2 ----
    int gb = bid - 640;           // 0..15
    int d0g = gb * 64;
    float* wr0 = smem;            // [0,512)
    float* wr1 = smem + 512;      // [512,1024)
    {
      int m = t;
      float w0 = 0.f, w1 = 0.f;
      for (int e = 0; e < En; ++e) {
        float w = W1[e * Mn + m];
        w0 += We[e] * w; w1 += We[En + e] * w;
      }
      float s = g1[m] * rsqrtf(rv1[m] + EPS_BN);
      wr0[m] = w0 * s; wr1[m] = w1 * s;
    }
    __syncthreads();
    int dl = t & 63, part = t >> 6;   // 8 m-parts x 64 d
    float p0 = 0.f, p1 = 0.f;
#pragma unroll 4
    for (int mm = 0; mm < 64; ++mm) {
      int m = part * 64 + mm;
      float wv = W2[m * Dn + d0g + dl];
      p0 += wr0[m] * wv; p1 += wr1[m] * wv;
    }
    float* pr = smem + 1024;
    pr[part * 64 + dl] = p0;
    pr[512 + part * 64 + dl] = p1;
    __syncthreads();
    if (t < 128) {
      int which = t >> 6, dd = d0g + (t & 63);
      float s2v = g2[dd] * rsqrtf(rv2[dd] + EPS_BN);
      float sum = 0.f;
#pragma unroll
      for (int pp = 0; pp < 8; ++pp) sum += pr[which * 512 + pp * 64 + (t & 63)];
      (which ? G1 : G0)[dd] = sum * s2v;
      if (which == 0) c2[dd] = b2[dd] * s2v + beta2[dd] - rm2[dd] * s2v;
    }
  }
}

// ---------------------------------------------------------------------------
// gemm_pool R7: wave owns TWO i rows (2i x 2jf x 4nf = 16 MFMA/ksl) sharing
// one A/B read set -> 8 ds_read_b128 per 16 MFMA (was 7 per 8): LDS traffic
// per MFMA HALVED (CU-phase 128KB ~ 1500cy < 2048cy MFMA -> MFMA-bound).
// Block = 8 i x 64 j x 128 d (4 waves), grid 2048, acc = 256 AGPR ->
// ~350 unified regs -> 1 wave/SIMD (launch_bounds(256,1)), 1 block/CU.
// MFMA clusters are 16 independent back-to-back ops; inter-cluster bubble is
// only 8 ds_read + 16 pkmax. DMA/L2 traffic also halves (2048 vs 4096 blocks
// staging the same 24KB/phase). XCD swizzle rebuilt for nwg=2048 (bijective).
// ---------------------------------------------------------------------------
__launch_bounds__(256, 1)
__global__ void gemm_pool(const __half* __restrict__ Agb,
                          const __half* __restrict__ Qgb,
                          const uint4* __restrict__ W2g,
                          const float* __restrict__ pos,
                          const float* __restrict__ G0, const float* __restrict__ G1,
                          const float* __restrict__ c2, float* __restrict__ out) {
  __shared__ uint4 SH[3584];  // A dbuf [0,1024) | B dbuf [1024,3072) | Q [3072,3584)

  // bijective XCD swizzle (nwg=2048, 8 XCDs): XCD x owns contiguous 256 swz
  // = 32 rt (4 frames: 256KB A + 256KB Q) x all 8 ct (1MB W2g) < 4MB L2.
  int wg  = blockIdx.x;
  int swz = (wg & 7) * 256 + (wg >> 3);
  int ct  = swz & 7;      // d-128 tile
  int rt  = swz >> 3;     // 0..255: (frame, i-octet)
  int f = rt >> 3, i0 = (rt & 7) * 8;

  int t = threadIdx.x, lane = t & 63, w = t >> 6;
  int ia = i0 + w * 2, ib = ia + 1;   // this wave's two i rows

  const uint4* aGL = (const uint4*)(Agb + (size_t)f * Pn * Mn) +
                     (size_t)(lane & 31) * 64 + (lane >> 5);
  const uint4* bGL = W2g + (size_t)(4 * ct) * 32 * 64 + lane;

  // stage phase p (K64): A 8 slots (ksl*2+jf), B 16 slots (ksl*4+nf)
  auto stageAB = [&](int p) {
    int buf = p & 1;
    dma16(aGL + (size_t)0 * 2048 + (p * 4 + w) * 2, SH + buf * 512 + (w * 2 + 0) * 64);
    dma16(aGL + (size_t)1 * 2048 + (p * 4 + w) * 2, SH + buf * 512 + (w * 2 + 1) * 64);
#pragma unroll
    for (int nf = 0; nf < 4; ++nf)
      dma16(bGL + (nf * 32 + p * 4 + w) * 64,
            SH + 1024 + buf * 1024 + (w * 4 + nf) * 64);
  };

  // prologue: Q rows for this wave's two i (once) + phase 0 A/B
  dma16((const uint4*)(Qgb + (size_t)(f * Pn + ia) * Mn) + lane,
        SH + 3072 + (w * 2 + 0) * 64);
  dma16((const uint4*)(Qgb + (size_t)(f * Pn + ib) * Mn) + lane,
        SH + 3072 + (w * 2 + 1) * 64);
  stageAB(0);

  f32x16 acc[2][2][4];  // [ii][jf][nf]
#pragma unroll
  for (int ii = 0; ii < 2; ++ii)
#pragma unroll
    for (int jf = 0; jf < 2; ++jf)
#pragma unroll
      for (int nf = 0; nf < 4; ++nf)
        acc[ii][jf][nf] = (f32x16){0.f,0.f,0.f,0.f,0.f,0.f,0.f,0.f,
                                   0.f,0.f,0.f,0.f,0.f,0.f,0.f,0.f};

  int qb0 = 3072 + (w * 2 + 0) * 64 + (lane >> 5);
  int qb1 = 3072 + (w * 2 + 1) * 64 + (lane >> 5);

#pragma unroll 1
  for (int p = 0; p < 8; ++p) {
    __syncthreads();                // buffer p ready (staged a full phase ago)
    if (p < 7) stageAB(p + 1);      // next phase's DMA overlaps this compute
    int ab = (p & 1) * 512 + lane;
    int bb = 1024 + (p & 1) * 1024 + lane;

#pragma unroll
    for (int ksl = 0; ksl < 4; ++ksl) {
      int ks = p * 4 + ksl;
      uint4 a0 = SH[ab + (ksl * 2 + 0) * 64];
      uint4 a1 = SH[ab + (ksl * 2 + 1) * 64];
      uint4 q0 = SH[qb0 + ks * 2];   // broadcast read
      uint4 q1 = SH[qb1 + ks * 2];   // broadcast read
      f16x8 af00, af01, af10, af11;
      mk2(a0, a1, q0, af00, af01);
      mk2(a0, a1, q1, af10, af11);
#pragma unroll
      for (int nf = 0; nf < 4; ++nf) {
        f16x8 bg = __builtin_bit_cast(f16x8, SH[bb + (ksl * 4 + nf) * 64]);
        acc[0][0][nf] = __builtin_amdgcn_mfma_f32_32x32x16_f16(af00, bg, acc[0][0][nf], 0, 0, 0);
        acc[0][1][nf] = __builtin_amdgcn_mfma_f32_32x32x16_f16(af01, bg, acc[0][1][nf], 0, 0, 0);
        acc[1][0][nf] = __builtin_amdgcn_mfma_f32_32x32x16_f16(af10, bg, acc[1][0][nf], 0, 0, 0);
        acc[1][1][nf] = __builtin_amdgcn_mfma_f32_32x32x16_f16(af11, bg, acc[1][1][nf], 0, 0, 0);
      }
    }
  }

  // ---- epilogue (in-wave): max over 64 j, then relu(S - R + c2) ----
  // C layout (32x32): col=lane&31, row=(reg&3)+8*(reg>>2)+4*(lane>>5).
#pragma unroll
  for (int ii = 0; ii < 2; ++ii) {
    int i = i0 + w * 2 + ii;
    float px = pos[(f * Pn + i) * 2], py = pos[(f * Pn + i) * 2 + 1];
#pragma unroll
    for (int nf = 0; nf < 4; ++nf) {
      float mx = -3.0e38f;
#pragma unroll
      for (int jf = 0; jf < 2; ++jf)
#pragma unroll
        for (int rg = 0; rg < 16; ++rg)
          mx = fmaxf(mx, acc[ii][jf][nf][rg]);
      mx = fmaxf(mx, __shfl_xor(mx, 32));
      if (lane < 32) {
        int d = ct * 128 + nf * 32 + (lane & 31);
        float r = px * G0[d] + py * G1[d];
        out[(f * Pn + i) * Dn + d] = fmaxf(mx - r + c2[d], 0.f);
      }
    }
  }
}

// ---------------------------------------------------------------------------
extern "C" void kernel_launch(void* const* d_in, const int* in_sizes, int n_in,
                              void* d_out, int out_size, void* d_ws, size_t ws_size,
                              hipStream_t stream) {
  const float* hs    = (const float*)d_in[0];
  const float* pos   = (const float*)d_in[1];
  // d_in[2] seq_start_end: unused (equal-size frames, P=64)
  const float* We    = (const float*)d_in[3];
  const float* be    = (const float*)d_in[4];
  const float* W1    = (const float*)d_in[5];
  const float* b1    = (const float*)d_in[6];
  const float* g1    = (const float*)d_in[7];
  const float* beta1 = (const float*)d_in[8];
  const float* W2    = (const float*)d_in[9];
  const float* b2    = (const float*)d_in[10];
  const float* g2    = (const float*)d_in[11];
  const float* beta2 = (const float*)d_in[12];
  const float* rm1   = (const float*)d_in[13];
  const float* rv1   = (const float*)d_in[14];
  const float* rm2   = (const float*)d_in[15];
  const float* rv2   = (const float*)d_in[16];

  char* ws = (char*)d_ws;
  // layout: c2 4KB | G0 4KB | G1 4KB | Agb 2MB | Qgb 2MB | W2g 1MB
  float* c2 = (float*)(ws + 0);
  float* G0 = (float*)(ws + 4096);
  float* G1 = (float*)(ws + 8192);
  __half* Agb = (__half*)(ws + 12288);
  __half* Qgb = (__half*)(ws + 12288 + 2097152);
  uint4* W2g = (uint4*)(ws + 12288 + 2 * 2097152);
  float* out = (float*)d_out;

  prep_all<<<656, 512, 0, stream>>>(hs, pos, We, be, W1, b1, g1, beta1, rm1, rv1,
                                    W2, b2, g2, beta2, rm2, rv2, Agb, Qgb, W2g,
                                    G0, G1, c2);
  gemm_pool<<<2048, 256, 0, stream>>>(Agb, Qgb, W2g, pos, G0, G1, c2, out);
}

// Round 8
// 234.215 us; speedup vs baseline: 1.2025x; 1.2025x over previous
//
#include <hip/hip_runtime.h>
#include <hip/hip_fp16.h>
#include <stdint.h>

#define EPS_BN 1e-5f

constexpr int Fn = 32;    // frames
constexpr int Pn = 64;    // peds per frame
constexpr int Bn = 2048;  // batch
constexpr int Hn = 128;   // h_dim
constexpr int En = 64;    // embed dim
constexpr int Mn = 512;   // GEMM K
constexpr int Dn = 1024;  // GEMM N

using f16x8   = __attribute__((ext_vector_type(8))) _Float16;
using f32x16  = __attribute__((ext_vector_type(16))) float;

static __device__ __forceinline__ unsigned short hfbits(float f) {
  return __builtin_bit_cast(unsigned short, __float2half(f));
}

// async 16B/lane global -> LDS (LDS base wave-uniform; HW adds lane*16)
static __device__ __forceinline__ void dma16(const uint4* g, const uint4* l) {
  __builtin_amdgcn_global_load_lds(
      (const __attribute__((address_space(1))) unsigned int*)g,
      (__attribute__((address_space(3))) unsigned int*)l, 16, 0, 0);
}

// packed fp16 max: one VOP3P instruction (ROCm header lacks __hmax2)
static __device__ __forceinline__ uint32_t pkmax(uint32_t a, uint32_t b) {
  uint32_t r;
  asm("v_pk_max_f16 %0, %1, %2" : "=v"(r) : "v"(a), "v"(b));
  return r;
}

// r0/r1 = fp16 max(a0,q), max(a1,q): 8 instructions total.
static __device__ __forceinline__ void mk2(uint4 a0, uint4 a1, uint4 q,
                                           f16x8& r0, f16x8& r1) {
  uint4 x0, x1;
#pragma unroll
  for (int v = 0; v < 4; ++v) {
    uint32_t qw = ((const uint32_t*)&q)[v];
    ((uint32_t*)&x0)[v] = pkmax(((const uint32_t*)&a0)[v], qw);
    ((uint32_t*)&x1)[v] = pkmax(((const uint32_t*)&a1)[v], qw);
  }
  r0 = __builtin_bit_cast(f16x8, x0);
  r1 = __builtin_bit_cast(f16x8, x1);
}

// ---------------------------------------------------------------------------
// prep_all: 656 blocks x 512 threads (unchanged).
// ---------------------------------------------------------------------------
__global__ void prep_all(const float* __restrict__ hs, const float* __restrict__ pos,
                         const float* __restrict__ We, const float* __restrict__ be,
                         const float* __restrict__ W1, const float* __restrict__ b1,
                         const float* __restrict__ g1, const float* __restrict__ beta1,
                         const float* __restrict__ rm1, const float* __restrict__ rv1,
                         const float* __restrict__ W2, const float* __restrict__ b2,
                         const float* __restrict__ g2, const float* __restrict__ beta2,
                         const float* __restrict__ rm2, const float* __restrict__ rv2,
                         __half* __restrict__ Agb, __half* __restrict__ Qgb,
                         uint4* __restrict__ W2g, float* __restrict__ G0,
                         float* __restrict__ G1, float* __restrict__ c2) {
  __shared__ float smem[64 * 65];
  int bid = blockIdx.x, t = threadIdx.x;
  if (bid < 512) {
    // ---- Ag/Qg for 4 batch rows, no LDS ----
    int rb = bid * 4, m = t;
    float w0 = 0.f, w1 = 0.f, c = 0.f;
    for (int e = 0; e < En; ++e) {
      float w = W1[e * Mn + m];
      w0 += We[e] * w; w1 += We[En + e] * w; c += be[e] * w;
    }
    c += b1[m];
    float s  = g1[m] * rsqrtf(rv1[m] + EPS_BN);
    float tt = beta1[m] - rm1[m] * s;
    float acc[4];
#pragma unroll
    for (int ri = 0; ri < 4; ++ri) acc[ri] = c;
#pragma unroll 4
    for (int e = 0; e < Hn; ++e) {
      float w = W1[(En + e) * Mn + m];
#pragma unroll
      for (int ri = 0; ri < 4; ++ri)
        acc[ri] += hs[(rb + ri) * Hn + e] * w;   // uniform addr -> s_load
    }
#pragma unroll
    for (int ri = 0; ri < 4; ++ri) {
      float q = pos[(rb + ri) * 2] * w0 + pos[(rb + ri) * 2 + 1] * w1;  // uniform
      Agb[(rb + ri) * Mn + m] = __float2half((acc[ri] + q) * s + tt);
      Qgb[(rb + ri) * Mn + m] = __float2half(q * s);
    }
  } else if (bid < 640) {
    // ---- W2 -> 32-col B-fragment granules (s2 folded), fp16 ----
    int b2i = bid - 512;                 // 0..127
    int d0 = (b2i & 15) * 64, k0 = (b2i >> 4) * 64;
    int col = t & 63, row8 = t >> 6;
#pragma unroll
    for (int rr = 0; rr < 8; ++rr) {
      int row = rr * 8 + row8;
      smem[row * 65 + col] = W2[(k0 + row) * Dn + d0 + col];  // [k_local][d_local]
    }
    __syncthreads();
    int lane = t & 63, q8 = t >> 6;
    int sel_n = q8 & 1, sel_ks = q8 >> 1;
    int dl = sel_n * 32 + (lane & 31), d = d0 + dl;
    float sf = g2[d] * rsqrtf(rv2[d] + EPS_BN);
    int kb = sel_ks * 16 + (lane >> 5) * 8;
    uint32_t wd[4];
#pragma unroll
    for (int h = 0; h < 4; ++h) {
      uint32_t u0 = hfbits(smem[(kb + 2 * h) * 65 + dl] * sf);
      uint32_t u1 = hfbits(smem[(kb + 2 * h + 1) * 65 + dl] * sf);
      wd[h] = u0 | (u1 << 16);
    }
    int n32 = (d0 >> 5) + sel_n;
    int ks  = (k0 >> 4) + sel_ks;
    W2g[(n32 * 32 + ks) * 64 + lane] = (uint4){wd[0], wd[1], wd[2], wd[3]};
  } else {
    // ---- G slice (64 d-cols) + c2 ----
    int gb = bid - 640;           // 0..15
    int d0g = gb * 64;
    float* wr0 = smem;            // [0,512)
    float* wr1 = smem + 512;      // [512,1024)
    {
      int m = t;
      float w0 = 0.f, w1 = 0.f;
      for (int e = 0; e < En; ++e) {
        float w = W1[e * Mn + m];
        w0 += We[e] * w; w1 += We[En + e] * w;
      }
      float s = g1[m] * rsqrtf(rv1[m] + EPS_BN);
      wr0[m] = w0 * s; wr1[m] = w1 * s;
    }
    __syncthreads();
    int dl = t & 63, part = t >> 6;   // 8 m-parts x 64 d
    float p0 = 0.f, p1 = 0.f;
#pragma unroll 4
    for (int mm = 0; mm < 64; ++mm) {
      int m = part * 64 + mm;
      float wv = W2[m * Dn + d0g + dl];
      p0 += wr0[m] * wv; p1 += wr1[m] * wv;
    }
    float* pr = smem + 1024;
    pr[part * 64 + dl] = p0;
    pr[512 + part * 64 + dl] = p1;
    __syncthreads();
    if (t < 128) {
      int which = t >> 6, dd = d0g + (t & 63);
      float s2v = g2[dd] * rsqrtf(rv2[dd] + EPS_BN);
      float sum = 0.f;
#pragma unroll
      for (int pp = 0; pp < 8; ++pp) sum += pr[which * 512 + pp * 64 + (t & 63)];
      (which ? G1 : G0)[dd] = sum * s2v;
      if (which == 0) c2[dd] = b2[dd] * s2v + beta2[dd] - rm2[dd] * s2v;
    }
  }
}

// ---------------------------------------------------------------------------
// gemm_pool R8: R4 tile (4i x 64j x 128d, 2 waves/SIMD, 212 regs — R7 lesson:
// bigger acc spills at 256 AGPR) + 3-deep LDS pipeline with COUNTED vmcnt
// (T3/T4): raw s_barrier + s_waitcnt vmcnt(6) instead of __syncthreads'
// vmcnt(0) drain. Per wave 6 DMAs/stage; prologue Q+s0+s1 (13 in flight);
// phase p: wait vmcnt(6) (retires exactly stage p), barrier, issue s(p+2),
// compute p. Loads span barriers with 2 phases to land -> barrier wait ~0.
// LDS 76KB (A 3x8K | B 3x16K | Q 4K), 2 blocks/CU (152KB). XCD swizzle kept.
// ---------------------------------------------------------------------------
__launch_bounds__(256, 2)
__global__ void gemm_pool(const __half* __restrict__ Agb,
                          const __half* __restrict__ Qgb,
                          const uint4* __restrict__ W2g,
                          const float* __restrict__ pos,
                          const float* __restrict__ G0, const float* __restrict__ G1,
                          const float* __restrict__ c2, float* __restrict__ out) {
  __shared__ uint4 SH[4864];  // A 3buf [0,1536) | B 3buf [1536,4608) | Q [4608,4864)

  // bijective XCD swizzle (nwg=4096, 8 XCDs): XCD x owns a contiguous rt chunk.
  int wg  = blockIdx.x;
  int swz = (wg & 7) * 512 + (wg >> 3);
  int ct  = swz & 7;     // d-128 tile
  int rt  = swz >> 3;    // (frame, i-quad)
  int f = rt >> 4, i0 = (rt & 15) * 4;

  int t = threadIdx.x, lane = t & 63, w = t >> 6;
  int i = i0 + w;                     // this wave's i

  const uint4* aGL = (const uint4*)(Agb + (size_t)f * Pn * Mn) +
                     (size_t)(lane & 31) * 64 + (lane >> 5);
  const uint4* bGL = W2g + (size_t)(4 * ct) * 32 * 64 + lane;

  // stage phase p (K64) into buf p%3: A 8 slots (ksl*2+jf), B 16 (ksl*4+nf)
  auto stageAB = [&](int p) {
    int buf = p % 3;
    dma16(aGL + (size_t)0 * 2048 + (p * 4 + w) * 2, SH + buf * 512 + (w * 2 + 0) * 64);
    dma16(aGL + (size_t)1 * 2048 + (p * 4 + w) * 2, SH + buf * 512 + (w * 2 + 1) * 64);
#pragma unroll
    for (int nf = 0; nf < 4; ++nf)
      dma16(bGL + (nf * 32 + p * 4 + w) * 64,
            SH + 1536 + buf * 1024 + (w * 4 + nf) * 64);
  };

  // prologue: Q row (1 DMA) + phases 0,1 (6 DMAs each) -> 13 in flight
  dma16((const uint4*)(Qgb + (size_t)(f * Pn + i) * Mn) + lane, SH + 4608 + w * 64);
  stageAB(0);
  stageAB(1);

  f32x16 acc[2][4];  // [jf][nf]
#pragma unroll
  for (int jf = 0; jf < 2; ++jf)
#pragma unroll
    for (int nf = 0; nf < 4; ++nf)
      acc[jf][nf] = (f32x16){0.f,0.f,0.f,0.f,0.f,0.f,0.f,0.f,
                             0.f,0.f,0.f,0.f,0.f,0.f,0.f,0.f};

  int qb = 4608 + w * 64 + (lane >> 5);

#pragma unroll 1
  for (int p = 0; p < 8; ++p) {
    // counted wait: retires exactly stage(p) (+Q at p==0); s(p+1) stays in flight
    if (p < 7) asm volatile("s_waitcnt vmcnt(6)" ::: "memory");
    else       asm volatile("s_waitcnt vmcnt(0)" ::: "memory");
    __builtin_amdgcn_s_barrier();        // all waves' stage(p) now visible
    __builtin_amdgcn_sched_barrier(0);   // pin: no ds_read hoisted above
    if (p < 6) stageAB(p + 2);           // buf (p+2)%3 == (p-1)%3: readers done
    int buf = p % 3;
    int ab = buf * 512 + lane;
    int bb = 1536 + buf * 1024 + lane;

#pragma unroll
    for (int ksl = 0; ksl < 4; ++ksl) {
      int ks = p * 4 + ksl;
      uint4 a0 = SH[ab + (ksl * 2 + 0) * 64];
      uint4 a1 = SH[ab + (ksl * 2 + 1) * 64];
      uint4 q  = SH[qb + ks * 2];   // broadcast read
      f16x8 af0, af1;
      mk2(a0, a1, q, af0, af1);
#pragma unroll
      for (int nf = 0; nf < 4; ++nf) {
        f16x8 bg = __builtin_bit_cast(f16x8, SH[bb + (ksl * 4 + nf) * 64]);
        acc[0][nf] = __builtin_amdgcn_mfma_f32_32x32x16_f16(af0, bg, acc[0][nf], 0, 0, 0);
        acc[1][nf] = __builtin_amdgcn_mfma_f32_32x32x16_f16(af1, bg, acc[1][nf], 0, 0, 0);
      }
    }
  }

  // ---- epilogue (in-wave): max over 64 j, then relu(S - R + c2) ----
  // C layout (32x32): col=lane&31, row=(reg&3)+8*(reg>>2)+4*(lane>>5).
  float px = pos[(f * Pn + i) * 2], py = pos[(f * Pn + i) * 2 + 1];
#pragma unroll
  for (int nf = 0; nf < 4; ++nf) {
    float mx = -3.0e38f;
#pragma unroll
    for (int jf = 0; jf < 2; ++jf)
#pragma unroll
      for (int rg = 0; rg < 16; ++rg)
        mx = fmaxf(mx, acc[jf][nf][rg]);
    mx = fmaxf(mx, __shfl_xor(mx, 32));
    if (lane < 32) {
      int d = ct * 128 + nf * 32 + (lane & 31);
      float r = px * G0[d] + py * G1[d];
      out[(f * Pn + i) * Dn + d] = fmaxf(mx - r + c2[d], 0.f);
    }
  }
}

// ---------------------------------------------------------------------------
extern "C" void kernel_launch(void* const* d_in, const int* in_sizes, int n_in,
                              void* d_out, int out_size, void* d_ws, size_t ws_size,
                              hipStream_t stream) {
  const float* hs    = (const float*)d_in[0];
  const float* pos   = (const float*)d_in[1];
  // d_in[2] seq_start_end: unused (equal-size frames, P=64)
  const float* We    = (const float*)d_in[3];
  const float* be    = (const float*)d_in[4];
  const float* W1    = (const float*)d_in[5];
  const float* b1    = (const float*)d_in[6];
  const float* g1    = (const float*)d_in[7];
  const float* beta1 = (const float*)d_in[8];
  const float* W2    = (const float*)d_in[9];
  const float* b2    = (const float*)d_in[10];
  const float* g2    = (const float*)d_in[11];
  const float* beta2 = (const float*)d_in[12];
  const float* rm1   = (const float*)d_in[13];
  const float* rv1   = (const float*)d_in[14];
  const float* rm2   = (const float*)d_in[15];
  const float* rv2   = (const float*)d_in[16];

  char* ws = (char*)d_ws;
  // layout: c2 4KB | G0 4KB | G1 4KB | Agb 2MB | Qgb 2MB | W2g 1MB
  float* c2 = (float*)(ws + 0);
  float* G0 = (float*)(ws + 4096);
  float* G1 = (float*)(ws + 8192);
  __half* Agb = (__half*)(ws + 12288);
  __half* Qgb = (__half*)(ws + 12288 + 2097152);
  uint4* W2g = (uint4*)(ws + 12288 + 2 * 2097152);
  float* out = (float*)d_out;

  prep_all<<<656, 512, 0, stream>>>(hs, pos, We, be, W1, b1, g1, beta1, rm1, rv1,
                                    W2, b2, g2, beta2, rm2, rv2, Agb, Qgb, W2g,
                                    G0, G1, c2);
  gemm_pool<<<4096, 256, 0, stream>>>(Agb, Qgb, W2g, pos, G0, G1, c2, out);
}